// Round 1
// baseline (1396.588 us; speedup 1.0000x reference)
//
#include <hip/hip_runtime.h>
#include <math.h>

// Problem constants
#define BB 8
#define LL 512
#define UU 24
#define DD 1024
#define HH 16
#define DH 64
#define TT 72
#define CSKN 1024
#define NVOCAB 54945

// ---------------------------------------------------------------------------
// Gather cls embeddings; write sem_cls_embs output and build trans_in (repeat 3x)
__global__ __launch_bounds__(256) void k_gather_cls(const float* __restrict__ hidden,
        const int* __restrict__ idx, float* __restrict__ sem_cls, float* __restrict__ trans_in)
{
    int bid = blockIdx.x; int b = bid / UU, u = bid % UU;
    int row = idx[b*UU + u];
    const float* src = hidden + ((size_t)(b*LL + row))*DD;
    float* d0 = trans_in + ((size_t)(b*TT + 3*u))*DD;
    float* sc = sem_cls + ((size_t)(b*UU + u))*DD;
    for (int d = threadIdx.x; d < DD; d += 256) {
        float v = src[d];
        sc[d] = v;
        d0[d] = v; d0[DD + d] = v; d0[2*DD + d] = v;
    }
}

// BatchNorm (inference) on emo_csk
__global__ void k_bn(const float* __restrict__ x, const float* __restrict__ g,
                     const float* __restrict__ be, const float* __restrict__ mu,
                     const float* __restrict__ var, float* __restrict__ y, int n)
{
    int i = blockIdx.x*256 + threadIdx.x;
    if (i >= n) return;
    int c = i % CSKN;
    y[i] = (x[i] - mu[c]) * (1.0f/sqrtf(var[c] + 1e-5f)) * g[c] + be[c];
}

// trans_in[:, 3u+2] += csk_proj[b,u]  for u < U-1
__global__ void k_addcsk(const float* __restrict__ proj, float* __restrict__ trans_in)
{
    int bid = blockIdx.x; int b = bid/(UU-1), u = bid%(UU-1);
    const float* p = proj + ((size_t)(b*UU + u))*DD;
    float* dst = trans_in + ((size_t)(b*TT + 3*u + 2))*DD;
    for (int d = threadIdx.x; d < DD; d += 256) dst[d] += p[d];
}

// ---------------------------------------------------------------------------
// Generic tiled f32 matmul: C[M,N] = act(A[M,K] @ Bmat[K,N] + bias)
// A may be the concat of A1 (first K1 cols, row stride K1) and A2 (rest, row
// stride K-K1).  EPI: 0 = none, 1 = +bias, 2 = sigmoid(+bias)
#define MM_TILE 64
#define MM_KB 16
template<int EPI>
__global__ __launch_bounds__(256) void mm_tiled(
        const float* __restrict__ A1, const float* __restrict__ A2, int K1,
        const float* __restrict__ Bm, const float* __restrict__ bias,
        float* __restrict__ C, int M, int N, int K)
{
    __shared__ float As[MM_KB][MM_TILE];   // [k][m]
    __shared__ float Bs[MM_KB][MM_TILE];   // [k][n]
    int tid = threadIdx.x;
    int tx = tid % 16, ty = tid / 16;
    int row0 = blockIdx.y * MM_TILE, col0 = blockIdx.x * MM_TILE;
    float acc[4][4] = {};
    int arow = tid / 4;          // 0..63
    int ak   = (tid % 4) * 4;    // 0,4,8,12
    int brow = tid / 16;         // 0..15
    int bcol = (tid % 16) * 4;   // 0..60

    for (int k0 = 0; k0 < K; k0 += MM_KB) {
        // load A tile (rows always in-bounds: M is a multiple of 64 here)
        {
            int kk = k0 + ak;
            const float* Arow;
            if (kk < K1) Arow = A1 + (size_t)(row0 + arow)*K1 + kk;
            else         Arow = A2 + (size_t)(row0 + arow)*(K - K1) + (kk - K1);
            #pragma unroll
            for (int j = 0; j < 4; ++j) As[ak + j][arow] = Arow[j];
        }
        // load B tile (guard N edge)
        {
            int kk = k0 + brow;
            #pragma unroll
            for (int j = 0; j < 4; ++j) {
                int c = col0 + bcol + j;
                Bs[brow][bcol + j] = (c < N) ? Bm[(size_t)kk * N + c] : 0.0f;
            }
        }
        __syncthreads();
        #pragma unroll
        for (int kk = 0; kk < MM_KB; ++kk) {
            float4 a4 = *(const float4*)&As[kk][ty*4];
            float4 b4 = *(const float4*)&Bs[kk][tx*4];
            float av[4] = {a4.x, a4.y, a4.z, a4.w};
            float bv[4] = {b4.x, b4.y, b4.z, b4.w};
            #pragma unroll
            for (int i2 = 0; i2 < 4; ++i2)
                #pragma unroll
                for (int j2 = 0; j2 < 4; ++j2) acc[i2][j2] += av[i2]*bv[j2];
        }
        __syncthreads();
    }
    #pragma unroll
    for (int i2 = 0; i2 < 4; ++i2) {
        int r = row0 + ty*4 + i2;
        #pragma unroll
        for (int j2 = 0; j2 < 4; ++j2) {
            int c = col0 + tx*4 + j2;
            if (c < N) {
                float v = acc[i2][j2];
                if (EPI >= 1) v += bias[c];
                if (EPI == 2) v = 1.0f/(1.0f + expf(-v));
                C[(size_t)r*N + c] = v;
            }
        }
    }
}

// ---------------------------------------------------------------------------
// Prefix counts of edge types along i: cnt[b,i,k,r] packed 8x u8 into uint2
__global__ void k_cnt(const int* __restrict__ et, uint2* __restrict__ cnt)
{
    int b = blockIdx.x;
    int k = threadIdx.x;
    if (k >= TT) return;
    unsigned lo = 0, hi = 0;
    for (int i = 0; i < TT; ++i) {
        int r = et[(b*TT + i)*TT + k];
        if (r < 4) lo += 1u << (8*r); else hi += 1u << (8*(r-4));
        cnt[(b*TT + i)*TT + k] = make_uint2(lo, hi);
    }
}

// A = Q + S_diag : Q[b,t,:] += sum_r cnt[b,t,t,r] * rel[r,:]   (in place on Q)
__global__ __launch_bounds__(256) void k_absdiag(float* __restrict__ Q,
        const uint2* __restrict__ cnt, const float* __restrict__ rel)
{
    int bt = blockIdx.x; int b = bt / TT, t = bt % TT;
    uint2 c = cnt[(b*TT + t)*TT + t];
    float cr[8];
    cr[0] = (float)( c.x        & 0xff); cr[1] = (float)((c.x >>  8) & 0xff);
    cr[2] = (float)((c.x >> 16) & 0xff); cr[3] = (float)((c.x >> 24) & 0xff);
    cr[4] = (float)( c.y        & 0xff); cr[5] = (float)((c.y >>  8) & 0xff);
    cr[6] = (float)((c.y >> 16) & 0xff); cr[7] = (float)((c.y >> 24) & 0xff);
    float* q = Q + (size_t)bt*DD;
    for (int d = threadIdx.x; d < DD; d += 256) {
        float a = q[d];
        #pragma unroll
        for (int r = 0; r < 8; ++r) a += cr[r]*rel[r*DD + d];
        q[d] = a;
    }
}

// AR[b,t,h,r] = sum_d' A[b,t,h*64+d'] * rel[r, h*64+d']
__global__ void k_ar(const float* __restrict__ Q, const float* __restrict__ rel,
                     float* __restrict__ AR)
{
    int bt = blockIdx.x;
    int t = threadIdx.x;            // 0..127 : h*8 + r
    int h = t / 8, r = t % 8;
    const float* q  = Q + (size_t)bt*DD + h*DH;
    const float* rl = rel + r*DD + h*DH;
    float s = 0.0f;
    #pragma unroll 16
    for (int d = 0; d < DH; ++d) s += q[d]*rl[d];
    AR[bt*128 + t] = s;
}

// Fused scores + softmax + PV per (b,h,i) row
__global__ __launch_bounds__(128) void k_attn_row(const float* __restrict__ A,
        const float* __restrict__ K, const float* __restrict__ V,
        const uint2* __restrict__ cnt, const float* __restrict__ AR,
        const int* __restrict__ mask, float* __restrict__ out)
{
    int bid = blockIdx.x;
    int b = bid / (HH*TT);
    int h = (bid / TT) % HH;
    int i = bid % TT;
    __shared__ float a_sh[DH];
    __shared__ float ar_sh[8];
    __shared__ float sc[TT];
    __shared__ float red[2];
    int t = threadIdx.x;
    if (t < DH)            a_sh[t]      = A[((size_t)(b*TT + i))*DD + h*DH + t];
    else if (t < DH + 8)   ar_sh[t-DH]  = AR[(b*TT + i)*128 + h*8 + (t - DH)];
    __syncthreads();
    if (t < TT) {
        const float* kr = K + ((size_t)(b*TT + t))*DD + h*DH;
        float s = 0.0f;
        #pragma unroll 16
        for (int d = 0; d < DH; ++d) s += a_sh[d]*kr[d];
        uint2 c = cnt[(b*TT + i)*TT + t];
        float s2 = (float)( c.x        & 0xff)*ar_sh[0] + (float)((c.x >>  8) & 0xff)*ar_sh[1]
                 + (float)((c.x >> 16) & 0xff)*ar_sh[2] + (float)((c.x >> 24) & 0xff)*ar_sh[3]
                 + (float)( c.y        & 0xff)*ar_sh[4] + (float)((c.y >>  8) & 0xff)*ar_sh[5]
                 + (float)((c.y >> 16) & 0xff)*ar_sh[6] + (float)((c.y >> 24) & 0xff)*ar_sh[7];
        int m = mask[(b*TT + i)*TT + t];
        sc[t] = (m == 0) ? -1e9f : (s + s2)*0.125f;
    }
    __syncthreads();
    if (t == 0) {
        float mx = -INFINITY;
        for (int k2 = 0; k2 < TT; ++k2) mx = fmaxf(mx, sc[k2]);
        float sm = 0.0f;
        for (int k2 = 0; k2 < TT; ++k2) sm += expf(sc[k2] - mx);
        red[0] = mx; red[1] = 1.0f/sm;
    }
    __syncthreads();
    if (t < TT) sc[t] = expf(sc[t] - red[0])*red[1];
    __syncthreads();
    if (t < DH) {
        float o = 0.0f;
        for (int k2 = 0; k2 < TT; ++k2) o += sc[k2]*V[((size_t)(b*TT + k2))*DD + h*DH + t];
        out[((size_t)(b*TT + i))*DD + h*DH + t] = o;
    }
}

// outputs = gate*trans + (1-gate)*inter
__global__ void k_blend(const float* __restrict__ g, const float* __restrict__ tr,
                        const float* __restrict__ in_, float* __restrict__ o, int n)
{
    int i = blockIdx.x*256 + threadIdx.x;
    if (i < n) { float gg = g[i]; o[i] = gg*tr[i] + (1.0f - gg)*in_[i]; }
}

// split outputs: emo_trans, delta (+ last_stra_state, last_delta)
__global__ __launch_bounds__(256) void k_final(const float* __restrict__ outs,
        const float* __restrict__ sem_cls, float* __restrict__ o_last_stra,
        float* __restrict__ o_emo, float* __restrict__ o_last_delta,
        float* __restrict__ delta)
{
    int bid = blockIdx.x; int b = bid / UU, u = bid % UU;
    const float* sem = outs + ((size_t)(b*TT + 3*u))*DD;
    const float* st  = sem + DD;
    const float* em  = st + DD;
    const float* sc  = sem_cls + ((size_t)(b*UU + u))*DD;
    float* de = delta + ((size_t)(b*UU + u))*DD;
    float* oe = o_emo + ((size_t)(b*UU + u))*DD;
    for (int d = threadIdx.x; d < DD; d += 256) {
        float dl = sem[d] - sc[d];
        de[d] = dl; oe[d] = em[d];
        if (u == UU-1) { o_last_stra[b*DD + d] = st[d]; o_last_delta[b*DD + d] = dl; }
    }
}

// strategy (8) and emotion (6) logits
__global__ void k_logits(const float* __restrict__ outs,
        const float* __restrict__ strW, const float* __restrict__ strB,
        const float* __restrict__ emoW, const float* __restrict__ emoB,
        float* __restrict__ o_str, float* __restrict__ o_emo)
{
    int bid = blockIdx.x; int b = bid / UU, u = bid % UU;
    int t = threadIdx.x;
    const float* st = outs + ((size_t)(b*TT + 3*u + 1))*DD;
    const float* em = st + DD;
    if (t < 8) {
        float s = strB[t];
        for (int k = 0; k < DD; ++k) s += st[k]*strW[k*8 + t];
        o_str[(b*UU + u)*8 + t] = s;
    } else if (t < 14) {
        int j = t - 8;
        float s = emoB[j];
        for (int k = 0; k < DD; ++k) s += em[k]*emoW[k*6 + j];
        o_emo[(b*UU + u)*6 + j] = s;
    }
}

// ---------------------------------------------------------------------------
extern "C" void kernel_launch(void* const* d_in, const int* in_sizes, int n_in,
                              void* d_out, int out_size, void* d_ws, size_t ws_size,
                              hipStream_t stream)
{
    const float* hidden  = (const float*)d_in[0];
    const float* emo_csk = (const float*)d_in[1];
    const float* Wq  = (const float*)d_in[2];
    const float* bq  = (const float*)d_in[3];
    const float* Wk  = (const float*)d_in[4];
    const float* bk  = (const float*)d_in[5];
    const float* Wv  = (const float*)d_in[6];
    const float* bv  = (const float*)d_in[7];
    const float* rel = (const float*)d_in[8];
    const float* fusW = (const float*)d_in[9];
    const float* fusB = (const float*)d_in[10];
    const float* bng = (const float*)d_in[11];
    const float* bnb = (const float*)d_in[12];
    const float* bnm = (const float*)d_in[13];
    const float* bnv = (const float*)d_in[14];
    const float* cskW = (const float*)d_in[15];
    const float* cskB = (const float*)d_in[16];
    const float* emoW = (const float*)d_in[17];
    const float* emoB = (const float*)d_in[18];
    const float* strW = (const float*)d_in[19];
    const float* strB = (const float*)d_in[20];
    const float* bowW = (const float*)d_in[21];
    const int* clsIdx = (const int*)d_in[22];
    const int* tGraph = (const int*)d_in[23];
    const int* iGraph = (const int*)d_in[24];
    const int* tEdge  = (const int*)d_in[25];
    const int* iEdge  = (const int*)d_in[26];

    float* out = (float*)d_out;
    float* o_last_stra  = out;             // B*D          = 8192
    float* o_emo_trans  = out + 8192;      // B*U*D        = 196608
    float* o_last_delta = out + 204800;    // B*D          = 8192
    float* o_sem_cls    = out + 212992;    // B*U*D        = 196608
    float* o_str_log    = out + 409600;    // B*U*8        = 1536
    float* o_emo_log    = out + 411136;    // B*U*6        = 1152
    float* o_bow        = out + 412288;    // B*U*VOCAB

    float* ws = (float*)d_ws;
    const int SZ_BTD = BB*TT*DD;   // 589824
    const int SZ_BUD = BB*UU*DD;   // 196608
    float* trans_in  = ws;
    float* Qb        = trans_in + SZ_BTD;
    float* Kb        = Qb + SZ_BTD;
    float* Vb        = Kb + SZ_BTD;
    float* trans_out = Vb + SZ_BTD;
    float* inter_out = trans_out + SZ_BTD;
    float* gate      = inter_out + SZ_BTD;
    float* outsB     = gate + SZ_BTD;
    float* csk_norm  = outsB + SZ_BTD;
    float* csk_proj  = csk_norm + SZ_BUD;
    float* delta     = csk_proj + SZ_BUD;
    float* ARb       = delta + SZ_BUD;                 // B*T*128
    uint2* cntb      = (uint2*)(ARb + BB*TT*128);      // B*T*T uint2

    // 1. gather cls + build trans_in; write sem_cls_embs
    k_gather_cls<<<dim3(BB*UU), dim3(256), 0, stream>>>(hidden, clsIdx, o_sem_cls, trans_in);
    // 2. batchnorm
    int nbn = BB*UU*CSKN;
    k_bn<<<dim3((nbn+255)/256), dim3(256), 0, stream>>>(emo_csk, bng, bnb, bnm, bnv, csk_norm, nbn);
    // 3. csk_proj = csk_norm @ csk_W + csk_b ; add into trans_in[:,2::3]
    mm_tiled<1><<<dim3(DD/64, 192/64), dim3(256), 0, stream>>>(csk_norm, nullptr, CSKN, cskW, cskB, csk_proj, 192, DD, CSKN);
    k_addcsk<<<dim3(BB*(UU-1)), dim3(256), 0, stream>>>(csk_proj, trans_in);

    // attention helper
    auto attention = [&](const float* x, const int* graph, const int* edge, float* ctx_out) {
        dim3 gq(DD/64, (BB*TT)/64);
        mm_tiled<1><<<gq, dim3(256), 0, stream>>>(x, nullptr, DD, Wq, bq, Qb, BB*TT, DD, DD);
        mm_tiled<1><<<gq, dim3(256), 0, stream>>>(x, nullptr, DD, Wk, bk, Kb, BB*TT, DD, DD);
        mm_tiled<1><<<gq, dim3(256), 0, stream>>>(x, nullptr, DD, Wv, bv, Vb, BB*TT, DD, DD);
        k_cnt<<<dim3(BB), dim3(128), 0, stream>>>(edge, cntb);
        k_absdiag<<<dim3(BB*TT), dim3(256), 0, stream>>>(Qb, cntb, rel);
        k_ar<<<dim3(BB*TT), dim3(128), 0, stream>>>(Qb, rel, ARb);
        k_attn_row<<<dim3(BB*HH*TT), dim3(128), 0, stream>>>(Qb, Kb, Vb, cntb, ARb, graph, ctx_out);
    };
    attention(trans_in, tGraph, tEdge, trans_out);
    attention(trans_out, iGraph, iEdge, inter_out);

    // fusion gate: sigmoid([trans_out, inter_out] @ fusion_W + fusion_b)
    mm_tiled<2><<<dim3(DD/64, (BB*TT)/64), dim3(256), 0, stream>>>(trans_out, inter_out, DD, fusW, fusB, gate, BB*TT, DD, 2*DD);
    k_blend<<<dim3((SZ_BTD+255)/256), dim3(256), 0, stream>>>(gate, trans_out, inter_out, outsB, SZ_BTD);

    // epilogue splits + small logits
    k_final<<<dim3(BB*UU), dim3(256), 0, stream>>>(outsB, o_sem_cls, o_last_stra, o_emo_trans, o_last_delta, delta);
    k_logits<<<dim3(BB*UU), dim3(64), 0, stream>>>(outsB, strW, strB, emoW, emoB, o_str_log, o_emo_log);

    // bow_logits = delta @ bow_W
    mm_tiled<0><<<dim3((NVOCAB+63)/64, 192/64), dim3(256), 0, stream>>>(delta, nullptr, CSKN, bowW, nullptr, o_bow, 192, NVOCAB, CSKN);
}

// Round 2
// 702.790 us; speedup vs baseline: 1.9872x; 1.9872x over previous
//
#include <hip/hip_runtime.h>
#include <math.h>

// Problem constants
#define BB 8
#define LL 512
#define UU 24
#define DD 1024
#define HH 16
#define DH 64
#define TT 72
#define CSKN 1024
#define NVOCAB 54945

typedef __attribute__((ext_vector_type(8))) short bf16x8;
typedef __attribute__((ext_vector_type(4))) float f32x4;

__device__ inline unsigned short f2b(float x) {
    unsigned u = __float_as_uint(x);
    unsigned r = u + 0x7FFFu + ((u >> 16) & 1u);
    return (unsigned short)(r >> 16);
}

// ---------------------------------------------------------------------------
// Gather cls embeddings; write sem_cls_embs output and build trans_in (repeat 3x)
__global__ __launch_bounds__(256) void k_gather_cls(const float* __restrict__ hidden,
        const int* __restrict__ idx, float* __restrict__ sem_cls, float* __restrict__ trans_in)
{
    int bid = blockIdx.x; int b = bid / UU, u = bid % UU;
    int row = idx[b*UU + u];
    const float* src = hidden + ((size_t)(b*LL + row))*DD;
    float* d0 = trans_in + ((size_t)(b*TT + 3*u))*DD;
    float* sc = sem_cls + ((size_t)(b*UU + u))*DD;
    for (int d = threadIdx.x; d < DD; d += 256) {
        float v = src[d];
        sc[d] = v;
        d0[d] = v; d0[DD + d] = v; d0[2*DD + d] = v;
    }
}

// BatchNorm (inference) on emo_csk
__global__ void k_bn(const float* __restrict__ x, const float* __restrict__ g,
                     const float* __restrict__ be, const float* __restrict__ mu,
                     const float* __restrict__ var, float* __restrict__ y, int n)
{
    int i = blockIdx.x*256 + threadIdx.x;
    if (i >= n) return;
    int c = i % CSKN;
    y[i] = (x[i] - mu[c]) * (1.0f/sqrtf(var[c] + 1e-5f)) * g[c] + be[c];
}

// trans_in[:, 3u+2] += csk_proj[b,u]  for u < U-1
__global__ void k_addcsk(const float* __restrict__ proj, float* __restrict__ trans_in)
{
    int bid = blockIdx.x; int b = bid/(UU-1), u = bid%(UU-1);
    const float* p = proj + ((size_t)(b*UU + u))*DD;
    float* dst = trans_in + ((size_t)(b*TT + 3*u + 2))*DD;
    for (int d = threadIdx.x; d < DD; d += 256) dst[d] += p[d];
}

// ---------------------------------------------------------------------------
// MFMA bf16 GEMM: C[M,N] = epi(A[M,K] @ B[K,N] + bias)
// A is f32 (optionally concat A1|A2 along K at K1), converted to bf16 while
// staging to LDS. B is f32, staged transposed to LDS as bf16.
// Wave grid: WROWS x WCOLS waves; each wave computes (MFRAG*16) x (NFRAG*16).
// BM = WROWS*MFRAG*16 (M must be a multiple of BM), BN = WCOLS*NFRAG*16.
// EPI: 0 = none, 1 = +bias, 2 = sigmoid(+bias)
template<int WROWS, int WCOLS, int MFRAG, int NFRAG, int EPI>
__global__ __launch_bounds__(256) void mm_mfma(
        const float* __restrict__ A1, const float* __restrict__ A2, int K1,
        const float* __restrict__ Bm, const float* __restrict__ bias,
        float* __restrict__ C, int M, int N, int K)
{
    constexpr int BM = WROWS*MFRAG*16;
    constexpr int BN = WCOLS*NFRAG*16;
    __shared__ unsigned short As[BM][40];   // 32 k + 8 pad (80B row stride)
    __shared__ unsigned short Bs[BN][40];   // transposed: [n][k]
    int tid = threadIdx.x;
    int wave = tid >> 6, lane = tid & 63;
    int l16 = lane & 15, g = lane >> 4;
    int wm = wave % WROWS, wn = wave / WROWS;
    int row0 = blockIdx.y * BM;
    int col0 = blockIdx.x * BN;
    f32x4 acc[MFRAG][NFRAG] = {};

    for (int k0 = 0; k0 < K; k0 += 32) {
        // stage A: thread -> (row, 8-wide k chunk)
        for (int idx = tid; idx < BM*4; idx += 256) {
            int r = idx >> 2, kq = idx & 3;
            int kk = k0 + kq*8;
            const float* src;
            if (kk < K1) src = A1 + (size_t)(row0 + r)*K1 + kk;
            else         src = A2 + (size_t)(row0 + r)*(K - K1) + (kk - K1);
            float4 v0 = *(const float4*)src;
            float4 v1 = *(const float4*)(src + 4);
            unsigned short* dst = &As[r][kq*8];
            dst[0]=f2b(v0.x); dst[1]=f2b(v0.y); dst[2]=f2b(v0.z); dst[3]=f2b(v0.w);
            dst[4]=f2b(v1.x); dst[5]=f2b(v1.y); dst[6]=f2b(v1.z); dst[7]=f2b(v1.w);
        }
        // stage B transposed: thread -> (col, 8-wide k chunk)
        for (int idx = tid; idx < BN*4; idx += 256) {
            int n = idx >> 2, kq = idx & 3;
            int cc = col0 + n;
            unsigned short* dst = &Bs[n][kq*8];
            if (cc < N) {
                const float* src = Bm + (size_t)(k0 + kq*8)*N + cc;
                #pragma unroll
                for (int j = 0; j < 8; ++j) dst[j] = f2b(src[(size_t)j*N]);
            } else {
                #pragma unroll
                for (int j = 0; j < 8; ++j) dst[j] = 0;
            }
        }
        __syncthreads();
        bf16x8 af[MFRAG], bfr[NFRAG];
        #pragma unroll
        for (int mf = 0; mf < MFRAG; ++mf)
            af[mf] = *(const bf16x8*)&As[wm*MFRAG*16 + mf*16 + l16][g*8];
        #pragma unroll
        for (int nf = 0; nf < NFRAG; ++nf)
            bfr[nf] = *(const bf16x8*)&Bs[wn*NFRAG*16 + nf*16 + l16][g*8];
        #pragma unroll
        for (int mf = 0; mf < MFRAG; ++mf)
            #pragma unroll
            for (int nf = 0; nf < NFRAG; ++nf)
                acc[mf][nf] = __builtin_amdgcn_mfma_f32_16x16x32_bf16(af[mf], bfr[nf], acc[mf][nf], 0, 0, 0);
        __syncthreads();
    }
    // epilogue: C[row=(g*4+r), col=l16] within each 16x16 fragment
    #pragma unroll
    for (int mf = 0; mf < MFRAG; ++mf) {
        #pragma unroll
        for (int nf = 0; nf < NFRAG; ++nf) {
            int cc = col0 + wn*NFRAG*16 + nf*16 + l16;
            if (cc < N) {
                #pragma unroll
                for (int r = 0; r < 4; ++r) {
                    int rr = row0 + wm*MFRAG*16 + mf*16 + g*4 + r;
                    float v = acc[mf][nf][r];
                    if (EPI >= 1) v += bias[cc];
                    if (EPI == 2) v = 1.0f/(1.0f + expf(-v));
                    C[(size_t)rr*N + cc] = v;
                }
            }
        }
    }
}

// ---------------------------------------------------------------------------
// Prefix counts of edge types along i: cnt[b,i,k,r] packed 8x u8 into uint2
__global__ void k_cnt(const int* __restrict__ et, uint2* __restrict__ cnt)
{
    int b = blockIdx.x;
    int k = threadIdx.x;
    if (k >= TT) return;
    unsigned lo = 0, hi = 0;
    for (int i = 0; i < TT; ++i) {
        int r = et[(b*TT + i)*TT + k];
        if (r < 4) lo += 1u << (8*r); else hi += 1u << (8*(r-4));
        cnt[(b*TT + i)*TT + k] = make_uint2(lo, hi);
    }
}

// A = Q + S_diag : Q[b,t,:] += sum_r cnt[b,t,t,r] * rel[r,:]   (in place on Q)
__global__ __launch_bounds__(256) void k_absdiag(float* __restrict__ Q,
        const uint2* __restrict__ cnt, const float* __restrict__ rel)
{
    int bt = blockIdx.x; int b = bt / TT, t = bt % TT;
    uint2 c = cnt[(b*TT + t)*TT + t];
    float cr[8];
    cr[0] = (float)( c.x        & 0xff); cr[1] = (float)((c.x >>  8) & 0xff);
    cr[2] = (float)((c.x >> 16) & 0xff); cr[3] = (float)((c.x >> 24) & 0xff);
    cr[4] = (float)( c.y        & 0xff); cr[5] = (float)((c.y >>  8) & 0xff);
    cr[6] = (float)((c.y >> 16) & 0xff); cr[7] = (float)((c.y >> 24) & 0xff);
    float* q = Q + (size_t)bt*DD;
    for (int d = threadIdx.x; d < DD; d += 256) {
        float a = q[d];
        #pragma unroll
        for (int r = 0; r < 8; ++r) a += cr[r]*rel[r*DD + d];
        q[d] = a;
    }
}

// AR[b,t,h,r] = sum_d' A[b,t,h*64+d'] * rel[r, h*64+d']
__global__ void k_ar(const float* __restrict__ Q, const float* __restrict__ rel,
                     float* __restrict__ AR)
{
    int bt = blockIdx.x;
    int t = threadIdx.x;            // 0..127 : h*8 + r
    int h = t / 8, r = t % 8;
    const float* q  = Q + (size_t)bt*DD + h*DH;
    const float* rl = rel + r*DD + h*DH;
    float s = 0.0f;
    #pragma unroll 16
    for (int d = 0; d < DH; ++d) s += q[d]*rl[d];
    AR[bt*128 + t] = s;
}

// Fused scores + softmax + PV per (b,h,i) row
__global__ __launch_bounds__(128) void k_attn_row(const float* __restrict__ A,
        const float* __restrict__ K, const float* __restrict__ V,
        const uint2* __restrict__ cnt, const float* __restrict__ AR,
        const int* __restrict__ mask, float* __restrict__ out)
{
    int bid = blockIdx.x;
    int b = bid / (HH*TT);
    int h = (bid / TT) % HH;
    int i = bid % TT;
    __shared__ float a_sh[DH];
    __shared__ float ar_sh[8];
    __shared__ float sc[TT];
    __shared__ float red[2];
    int t = threadIdx.x;
    if (t < DH)            a_sh[t]      = A[((size_t)(b*TT + i))*DD + h*DH + t];
    else if (t < DH + 8)   ar_sh[t-DH]  = AR[(b*TT + i)*128 + h*8 + (t - DH)];
    __syncthreads();
    if (t < TT) {
        const float* kr = K + ((size_t)(b*TT + t))*DD + h*DH;
        float s = 0.0f;
        #pragma unroll 16
        for (int d = 0; d < DH; ++d) s += a_sh[d]*kr[d];
        uint2 c = cnt[(b*TT + i)*TT + t];
        float s2 = (float)( c.x        & 0xff)*ar_sh[0] + (float)((c.x >>  8) & 0xff)*ar_sh[1]
                 + (float)((c.x >> 16) & 0xff)*ar_sh[2] + (float)((c.x >> 24) & 0xff)*ar_sh[3]
                 + (float)( c.y        & 0xff)*ar_sh[4] + (float)((c.y >>  8) & 0xff)*ar_sh[5]
                 + (float)((c.y >> 16) & 0xff)*ar_sh[6] + (float)((c.y >> 24) & 0xff)*ar_sh[7];
        int m = mask[(b*TT + i)*TT + t];
        sc[t] = (m == 0) ? -1e9f : (s + s2)*0.125f;
    }
    __syncthreads();
    if (t == 0) {
        float mx = -INFINITY;
        for (int k2 = 0; k2 < TT; ++k2) mx = fmaxf(mx, sc[k2]);
        float sm = 0.0f;
        for (int k2 = 0; k2 < TT; ++k2) sm += expf(sc[k2] - mx);
        red[0] = mx; red[1] = 1.0f/sm;
    }
    __syncthreads();
    if (t < TT) sc[t] = expf(sc[t] - red[0])*red[1];
    __syncthreads();
    if (t < DH) {
        float o = 0.0f;
        for (int k2 = 0; k2 < TT; ++k2) o += sc[k2]*V[((size_t)(b*TT + k2))*DD + h*DH + t];
        out[((size_t)(b*TT + i))*DD + h*DH + t] = o;
    }
}

// outputs = gate*trans + (1-gate)*inter
__global__ void k_blend(const float* __restrict__ g, const float* __restrict__ tr,
                        const float* __restrict__ in_, float* __restrict__ o, int n)
{
    int i = blockIdx.x*256 + threadIdx.x;
    if (i < n) { float gg = g[i]; o[i] = gg*tr[i] + (1.0f - gg)*in_[i]; }
}

// split outputs: emo_trans, delta (+ last_stra_state, last_delta)
__global__ __launch_bounds__(256) void k_final(const float* __restrict__ outs,
        const float* __restrict__ sem_cls, float* __restrict__ o_last_stra,
        float* __restrict__ o_emo, float* __restrict__ o_last_delta,
        float* __restrict__ delta)
{
    int bid = blockIdx.x; int b = bid / UU, u = bid % UU;
    const float* sem = outs + ((size_t)(b*TT + 3*u))*DD;
    const float* st  = sem + DD;
    const float* em  = st + DD;
    const float* sc  = sem_cls + ((size_t)(b*UU + u))*DD;
    float* de = delta + ((size_t)(b*UU + u))*DD;
    float* oe = o_emo + ((size_t)(b*UU + u))*DD;
    for (int d = threadIdx.x; d < DD; d += 256) {
        float dl = sem[d] - sc[d];
        de[d] = dl; oe[d] = em[d];
        if (u == UU-1) { o_last_stra[b*DD + d] = st[d]; o_last_delta[b*DD + d] = dl; }
    }
}

// strategy (8) and emotion (6) logits
__global__ void k_logits(const float* __restrict__ outs,
        const float* __restrict__ strW, const float* __restrict__ strB,
        const float* __restrict__ emoW, const float* __restrict__ emoB,
        float* __restrict__ o_str, float* __restrict__ o_emo)
{
    int bid = blockIdx.x; int b = bid / UU, u = bid % UU;
    int t = threadIdx.x;
    const float* st = outs + ((size_t)(b*TT + 3*u + 1))*DD;
    const float* em = st + DD;
    if (t < 8) {
        float s = strB[t];
        for (int k = 0; k < DD; ++k) s += st[k]*strW[k*8 + t];
        o_str[(b*UU + u)*8 + t] = s;
    } else if (t < 14) {
        int j = t - 8;
        float s = emoB[j];
        for (int k = 0; k < DD; ++k) s += em[k]*emoW[k*6 + j];
        o_emo[(b*UU + u)*6 + j] = s;
    }
}

// ---------------------------------------------------------------------------
extern "C" void kernel_launch(void* const* d_in, const int* in_sizes, int n_in,
                              void* d_out, int out_size, void* d_ws, size_t ws_size,
                              hipStream_t stream)
{
    const float* hidden  = (const float*)d_in[0];
    const float* emo_csk = (const float*)d_in[1];
    const float* Wq  = (const float*)d_in[2];
    const float* bq  = (const float*)d_in[3];
    const float* Wk  = (const float*)d_in[4];
    const float* bk  = (const float*)d_in[5];
    const float* Wv  = (const float*)d_in[6];
    const float* bv  = (const float*)d_in[7];
    const float* rel = (const float*)d_in[8];
    const float* fusW = (const float*)d_in[9];
    const float* fusB = (const float*)d_in[10];
    const float* bng = (const float*)d_in[11];
    const float* bnb = (const float*)d_in[12];
    const float* bnm = (const float*)d_in[13];
    const float* bnv = (const float*)d_in[14];
    const float* cskW = (const float*)d_in[15];
    const float* cskB = (const float*)d_in[16];
    const float* emoW = (const float*)d_in[17];
    const float* emoB = (const float*)d_in[18];
    const float* strW = (const float*)d_in[19];
    const float* strB = (const float*)d_in[20];
    const float* bowW = (const float*)d_in[21];
    const int* clsIdx = (const int*)d_in[22];
    const int* tGraph = (const int*)d_in[23];
    const int* iGraph = (const int*)d_in[24];
    const int* tEdge  = (const int*)d_in[25];
    const int* iEdge  = (const int*)d_in[26];

    float* out = (float*)d_out;
    float* o_last_stra  = out;             // B*D          = 8192
    float* o_emo_trans  = out + 8192;      // B*U*D        = 196608
    float* o_last_delta = out + 204800;    // B*D          = 8192
    float* o_sem_cls    = out + 212992;    // B*U*D        = 196608
    float* o_str_log    = out + 409600;    // B*U*8        = 1536
    float* o_emo_log    = out + 411136;    // B*U*6        = 1152
    float* o_bow        = out + 412288;    // B*U*VOCAB

    float* ws = (float*)d_ws;
    const int SZ_BTD = BB*TT*DD;   // 589824
    const int SZ_BUD = BB*UU*DD;   // 196608
    float* trans_in  = ws;
    float* Qb        = trans_in + SZ_BTD;
    float* Kb        = Qb + SZ_BTD;
    float* Vb        = Kb + SZ_BTD;
    float* trans_out = Vb + SZ_BTD;
    float* inter_out = trans_out + SZ_BTD;
    float* gate      = inter_out + SZ_BTD;
    float* outsB     = gate + SZ_BTD;
    float* csk_norm  = outsB + SZ_BTD;
    float* csk_proj  = csk_norm + SZ_BUD;
    float* delta     = csk_proj + SZ_BUD;
    float* ARb       = delta + SZ_BUD;                 // B*T*128
    uint2* cntb      = (uint2*)(ARb + BB*TT*128);      // B*T*T uint2

    // 1. gather cls + build trans_in; write sem_cls_embs
    k_gather_cls<<<dim3(BB*UU), dim3(256), 0, stream>>>(hidden, clsIdx, o_sem_cls, trans_in);
    // 2. batchnorm
    int nbn = BB*UU*CSKN;
    k_bn<<<dim3((nbn+255)/256), dim3(256), 0, stream>>>(emo_csk, bng, bnb, bnm, bnv, csk_norm, nbn);
    // 3. csk_proj = csk_norm @ csk_W + csk_b ; add into trans_in[:,2::3]
    mm_mfma<2,2,2,2,1><<<dim3(DD/64, 192/64), dim3(256), 0, stream>>>(csk_norm, nullptr, CSKN, cskW, cskB, csk_proj, 192, DD, CSKN);
    k_addcsk<<<dim3(BB*(UU-1)), dim3(256), 0, stream>>>(csk_proj, trans_in);

    // attention helper
    auto attention = [&](const float* x, const int* graph, const int* edge, float* ctx_out) {
        dim3 gq(DD/64, (BB*TT)/64);
        mm_mfma<2,2,2,2,1><<<gq, dim3(256), 0, stream>>>(x, nullptr, DD, Wq, bq, Qb, BB*TT, DD, DD);
        mm_mfma<2,2,2,2,1><<<gq, dim3(256), 0, stream>>>(x, nullptr, DD, Wk, bk, Kb, BB*TT, DD, DD);
        mm_mfma<2,2,2,2,1><<<gq, dim3(256), 0, stream>>>(x, nullptr, DD, Wv, bv, Vb, BB*TT, DD, DD);
        k_cnt<<<dim3(BB), dim3(128), 0, stream>>>(edge, cntb);
        k_absdiag<<<dim3(BB*TT), dim3(256), 0, stream>>>(Qb, cntb, rel);
        k_ar<<<dim3(BB*TT), dim3(128), 0, stream>>>(Qb, rel, ARb);
        k_attn_row<<<dim3(BB*HH*TT), dim3(128), 0, stream>>>(Qb, Kb, Vb, cntb, ARb, graph, ctx_out);
    };
    attention(trans_in, tGraph, tEdge, trans_out);
    attention(trans_out, iGraph, iEdge, inter_out);

    // fusion gate: sigmoid([trans_out, inter_out] @ fusion_W + fusion_b)
    mm_mfma<2,2,2,2,2><<<dim3(DD/64, (BB*TT)/64), dim3(256), 0, stream>>>(trans_out, inter_out, DD, fusW, fusB, gate, BB*TT, DD, 2*DD);
    k_blend<<<dim3((SZ_BTD+255)/256), dim3(256), 0, stream>>>(gate, trans_out, inter_out, outsB, SZ_BTD);

    // epilogue splits + small logits
    k_final<<<dim3(BB*UU), dim3(256), 0, stream>>>(outsB, o_sem_cls, o_last_stra, o_emo_trans, o_last_delta, delta);
    k_logits<<<dim3(BB*UU), dim3(64), 0, stream>>>(outsB, strW, strB, emoW, emoB, o_str_log, o_emo_log);

    // bow_logits = delta @ bow_W  (BM=192 -> one row-block; bow_W fetched once)
    mm_mfma<4,1,3,4,0><<<dim3((NVOCAB+63)/64, 1), dim3(256), 0, stream>>>(delta, nullptr, CSKN, bowW, nullptr, o_bow, 192, NVOCAB, CSKN);
}

// Round 3
// 567.015 us; speedup vs baseline: 2.4631x; 1.2395x over previous
//
#include <hip/hip_runtime.h>
#include <math.h>

// Problem constants
#define BB 8
#define LL 512
#define UU 24
#define DD 1024
#define HH 16
#define DH 64
#define TT 72
#define CSKN 1024
#define NVOCAB 54945

typedef __attribute__((ext_vector_type(8))) short bf16x8;
typedef __attribute__((ext_vector_type(4))) float f32x4;

__device__ inline unsigned short f2b(float x) {
    unsigned u = __float_as_uint(x);
    unsigned r = u + 0x7FFFu + ((u >> 16) & 1u);
    return (unsigned short)(r >> 16);
}

// ---------------------------------------------------------------------------
__global__ __launch_bounds__(256) void k_gather_cls(const float* __restrict__ hidden,
        const int* __restrict__ idx, float* __restrict__ sem_cls, float* __restrict__ trans_in)
{
    int bid = blockIdx.x; int b = bid / UU, u = bid % UU;
    int row = idx[b*UU + u];
    const float* src = hidden + ((size_t)(b*LL + row))*DD;
    float* d0 = trans_in + ((size_t)(b*TT + 3*u))*DD;
    float* sc = sem_cls + ((size_t)(b*UU + u))*DD;
    for (int d = threadIdx.x; d < DD; d += 256) {
        float v = src[d];
        sc[d] = v;
        d0[d] = v; d0[DD + d] = v; d0[2*DD + d] = v;
    }
}

__global__ void k_bn(const float* __restrict__ x, const float* __restrict__ g,
                     const float* __restrict__ be, const float* __restrict__ mu,
                     const float* __restrict__ var, float* __restrict__ y, int n)
{
    int i = blockIdx.x*256 + threadIdx.x;
    if (i >= n) return;
    int c = i % CSKN;
    y[i] = (x[i] - mu[c]) * (1.0f/sqrtf(var[c] + 1e-5f)) * g[c] + be[c];
}

__global__ void k_addcsk(const float* __restrict__ proj, float* __restrict__ trans_in)
{
    int bid = blockIdx.x; int b = bid/(UU-1), u = bid%(UU-1);
    const float* p = proj + ((size_t)(b*UU + u))*DD;
    float* dst = trans_in + ((size_t)(b*TT + 3*u + 2))*DD;
    for (int d = threadIdx.x; d < DD; d += 256) dst[d] += p[d];
}

// ---------------------------------------------------------------------------
// Generic MFMA bf16 GEMM (256 thr): C = epi(A @ B + bias)
// EPI: 0 none, 1 +bias, 2 sigmoid(+bias), 3 gate-blend: C = g*ep1 + (1-g)*ep2
template<int WROWS, int WCOLS, int MFRAG, int NFRAG, int EPI>
__global__ __launch_bounds__(256) void mm_mfma(
        const float* __restrict__ A1, const float* __restrict__ A2, int K1,
        const float* __restrict__ Bm, const float* __restrict__ bias,
        const float* __restrict__ ep1, const float* __restrict__ ep2,
        float* __restrict__ C, int M, int N, int K)
{
    constexpr int BM = WROWS*MFRAG*16;
    constexpr int BN = WCOLS*NFRAG*16;
    __shared__ unsigned short As[BM][40];
    __shared__ unsigned short Bs[BN][40];
    int tid = threadIdx.x;
    int wave = tid >> 6, lane = tid & 63;
    int l16 = lane & 15, g = lane >> 4;
    int wm = wave % WROWS, wn = wave / WROWS;
    int row0 = blockIdx.y * BM;
    int col0 = blockIdx.x * BN;
    f32x4 acc[MFRAG][NFRAG] = {};

    for (int k0 = 0; k0 < K; k0 += 32) {
        for (int idx = tid; idx < BM*4; idx += 256) {
            int r = idx >> 2, kq = idx & 3;
            int kk = k0 + kq*8;
            const float* src;
            if (kk < K1) src = A1 + (size_t)(row0 + r)*K1 + kk;
            else         src = A2 + (size_t)(row0 + r)*(K - K1) + (kk - K1);
            float4 v0 = *(const float4*)src;
            float4 v1 = *(const float4*)(src + 4);
            unsigned short* dst = &As[r][kq*8];
            dst[0]=f2b(v0.x); dst[1]=f2b(v0.y); dst[2]=f2b(v0.z); dst[3]=f2b(v0.w);
            dst[4]=f2b(v1.x); dst[5]=f2b(v1.y); dst[6]=f2b(v1.z); dst[7]=f2b(v1.w);
        }
        // B staged transposed via coalesced row reads: 32k x BN f32 tile
        {
            int nquads = BN/4;  // float4 cols per row
            // 256 threads cover 32*nquads float4s in (32*nquads)/256 passes
            for (int p = 0; p < (32*nquads)/256; ++p) {
                int idx = p*256 + tid;
                int kk = idx / nquads;
                int j0 = (idx % nquads)*4;
                int cc = col0 + j0;
                float4 v;
                if (cc + 3 < N) v = *(const float4*)&Bm[(size_t)(k0 + kk)*N + cc];
                else {
                    float t0 = (cc   < N) ? Bm[(size_t)(k0+kk)*N + cc  ] : 0.0f;
                    float t1 = (cc+1 < N) ? Bm[(size_t)(k0+kk)*N + cc+1] : 0.0f;
                    float t2 = (cc+2 < N) ? Bm[(size_t)(k0+kk)*N + cc+2] : 0.0f;
                    float t3 = (cc+3 < N) ? Bm[(size_t)(k0+kk)*N + cc+3] : 0.0f;
                    v = make_float4(t0,t1,t2,t3);
                }
                Bs[j0  ][kk] = f2b(v.x);
                Bs[j0+1][kk] = f2b(v.y);
                Bs[j0+2][kk] = f2b(v.z);
                Bs[j0+3][kk] = f2b(v.w);
            }
        }
        __syncthreads();
        bf16x8 af[MFRAG], bfr[NFRAG];
        #pragma unroll
        for (int mf = 0; mf < MFRAG; ++mf)
            af[mf] = *(const bf16x8*)&As[wm*MFRAG*16 + mf*16 + l16][g*8];
        #pragma unroll
        for (int nf = 0; nf < NFRAG; ++nf)
            bfr[nf] = *(const bf16x8*)&Bs[wn*NFRAG*16 + nf*16 + l16][g*8];
        #pragma unroll
        for (int mf = 0; mf < MFRAG; ++mf)
            #pragma unroll
            for (int nf = 0; nf < NFRAG; ++nf)
                acc[mf][nf] = __builtin_amdgcn_mfma_f32_16x16x32_bf16(af[mf], bfr[nf], acc[mf][nf], 0, 0, 0);
        __syncthreads();
    }
    #pragma unroll
    for (int mf = 0; mf < MFRAG; ++mf) {
        #pragma unroll
        for (int nf = 0; nf < NFRAG; ++nf) {
            int cc = col0 + wn*NFRAG*16 + nf*16 + l16;
            if (cc < N) {
                #pragma unroll
                for (int r = 0; r < 4; ++r) {
                    int rr = row0 + wm*MFRAG*16 + mf*16 + g*4 + r;
                    float v = acc[mf][nf][r];
                    if (EPI >= 1) v += bias[cc];
                    if (EPI == 2) v = 1.0f/(1.0f + expf(-v));
                    if (EPI == 3) {
                        float gg = 1.0f/(1.0f + expf(-v));
                        float tv = ep1[(size_t)rr*N + cc];
                        float iv = ep2[(size_t)rr*N + cc];
                        v = gg*tv + (1.0f - gg)*iv;
                    }
                    C[(size_t)rr*N + cc] = v;
                }
            }
        }
    }
}

// ---------------------------------------------------------------------------
// Fused Q/K/V projection GEMM: x[576,1024] @ {Wq,Wk,Wv} -> Qb,Kb,Vb
// Grid (48, 9): blockIdx.x>>4 selects which of Q/K/V. BM=BN=64, 4 waves.
__global__ __launch_bounds__(256) void mm_qkv(
        const float* __restrict__ x,
        const float* __restrict__ W0, const float* __restrict__ W1, const float* __restrict__ W2,
        const float* __restrict__ b0, const float* __restrict__ b1, const float* __restrict__ b2,
        float* __restrict__ C0, float* __restrict__ C1, float* __restrict__ C2)
{
    __shared__ unsigned short As[64][40];
    __shared__ unsigned short Bs[64][40];
    int which = blockIdx.x >> 4;
    int col0 = (blockIdx.x & 15) * 64;
    int row0 = blockIdx.y * 64;
    const float* W  = (which == 0) ? W0 : (which == 1) ? W1 : W2;
    const float* bb = (which == 0) ? b0 : (which == 1) ? b1 : b2;
    float*       C  = (which == 0) ? C0 : (which == 1) ? C1 : C2;
    int tid = threadIdx.x;
    int wave = tid >> 6, lane = tid & 63;
    int l16 = lane & 15, g = lane >> 4;
    int wm = wave & 1, wn = wave >> 1;
    f32x4 acc[2][2] = {};

    for (int k0 = 0; k0 < DD; k0 += 32) {
        {   // A: 64 rows x 32 k
            int r = tid >> 2, kq = tid & 3;
            const float* src = x + (size_t)(row0 + r)*DD + k0 + kq*8;
            float4 v0 = *(const float4*)src;
            float4 v1 = *(const float4*)(src + 4);
            unsigned short* dst = &As[r][kq*8];
            dst[0]=f2b(v0.x); dst[1]=f2b(v0.y); dst[2]=f2b(v0.z); dst[3]=f2b(v0.w);
            dst[4]=f2b(v1.x); dst[5]=f2b(v1.y); dst[6]=f2b(v1.z); dst[7]=f2b(v1.w);
        }
        #pragma unroll
        for (int p = 0; p < 2; ++p) {   // B: coalesced rows, transposed write
            int idx = p*256 + tid;
            int kk = idx >> 4;          // 0..31
            int j0 = (idx & 15)*4;
            float4 v = *(const float4*)&W[(size_t)(k0 + kk)*DD + col0 + j0];
            Bs[j0  ][kk] = f2b(v.x);
            Bs[j0+1][kk] = f2b(v.y);
            Bs[j0+2][kk] = f2b(v.z);
            Bs[j0+3][kk] = f2b(v.w);
        }
        __syncthreads();
        bf16x8 af[2], bfr[2];
        #pragma unroll
        for (int mf = 0; mf < 2; ++mf) af[mf] = *(const bf16x8*)&As[wm*32 + mf*16 + l16][g*8];
        #pragma unroll
        for (int nf = 0; nf < 2; ++nf) bfr[nf] = *(const bf16x8*)&Bs[wn*32 + nf*16 + l16][g*8];
        #pragma unroll
        for (int mf = 0; mf < 2; ++mf)
            #pragma unroll
            for (int nf = 0; nf < 2; ++nf)
                acc[mf][nf] = __builtin_amdgcn_mfma_f32_16x16x32_bf16(af[mf], bfr[nf], acc[mf][nf], 0, 0, 0);
        __syncthreads();
    }
    #pragma unroll
    for (int mf = 0; mf < 2; ++mf)
        #pragma unroll
        for (int nf = 0; nf < 2; ++nf) {
            int cc = col0 + wn*32 + nf*16 + l16;
            float bv = bb[cc];
            #pragma unroll
            for (int r = 0; r < 4; ++r) {
                int rr = row0 + wm*32 + mf*16 + g*4 + r;
                C[(size_t)rr*DD + cc] = acc[mf][nf][r] + bv;
            }
        }
}

// ---------------------------------------------------------------------------
// bow GEMM: delta[192,1024] @ bowW[1024,54945] -> o_bow.  512 thr, 8 waves.
// BM=192 (whole M), BN=64.  Coalesced B row reads + transposed LDS write.
__global__ __launch_bounds__(512) void mm_bow(
        const float* __restrict__ A, const float* __restrict__ Bm, float* __restrict__ C)
{
    __shared__ unsigned short As[192][40];
    __shared__ unsigned short Bs[64][40];
    int tid = threadIdx.x;
    int wave = tid >> 6, lane = tid & 63;
    int l16 = lane & 15, g = lane >> 4;
    int wm = wave & 3;       // 0..3 -> 48-row stripes
    int wn = wave >> 2;      // 0..1 -> 32-col halves
    int col0 = blockIdx.x * 64;
    const int N = NVOCAB;
    f32x4 acc[3][2] = {};

    for (int k0 = 0; k0 < CSKN; k0 += 32) {
        for (int idx = tid; idx < 192*4; idx += 512) {
            int r = idx >> 2, kq = idx & 3;
            const float* src = A + (size_t)r*CSKN + k0 + kq*8;
            float4 v0 = *(const float4*)src;
            float4 v1 = *(const float4*)(src + 4);
            unsigned short* dst = &As[r][kq*8];
            dst[0]=f2b(v0.x); dst[1]=f2b(v0.y); dst[2]=f2b(v0.z); dst[3]=f2b(v0.w);
            dst[4]=f2b(v1.x); dst[5]=f2b(v1.y); dst[6]=f2b(v1.z); dst[7]=f2b(v1.w);
        }
        {   // B tile 32k x 64n: 512 float4 loads, one per thread
            int kk = tid >> 4;          // 0..31
            int j0 = (tid & 15)*4;
            int cc = col0 + j0;
            float4 v;
            if (cc + 3 < N) v = *(const float4*)&Bm[(size_t)(k0 + kk)*N + cc];
            else {
                float t0 = (cc   < N) ? Bm[(size_t)(k0+kk)*N + cc  ] : 0.0f;
                float t1 = (cc+1 < N) ? Bm[(size_t)(k0+kk)*N + cc+1] : 0.0f;
                float t2 = (cc+2 < N) ? Bm[(size_t)(k0+kk)*N + cc+2] : 0.0f;
                float t3 = (cc+3 < N) ? Bm[(size_t)(k0+kk)*N + cc+3] : 0.0f;
                v = make_float4(t0,t1,t2,t3);
            }
            Bs[j0  ][kk] = f2b(v.x);
            Bs[j0+1][kk] = f2b(v.y);
            Bs[j0+2][kk] = f2b(v.z);
            Bs[j0+3][kk] = f2b(v.w);
        }
        __syncthreads();
        bf16x8 af[3], bfr[2];
        #pragma unroll
        for (int mf = 0; mf < 3; ++mf) af[mf] = *(const bf16x8*)&As[wm*48 + mf*16 + l16][g*8];
        #pragma unroll
        for (int nf = 0; nf < 2; ++nf) bfr[nf] = *(const bf16x8*)&Bs[wn*32 + nf*16 + l16][g*8];
        #pragma unroll
        for (int mf = 0; mf < 3; ++mf)
            #pragma unroll
            for (int nf = 0; nf < 2; ++nf)
                acc[mf][nf] = __builtin_amdgcn_mfma_f32_16x16x32_bf16(af[mf], bfr[nf], acc[mf][nf], 0, 0, 0);
        __syncthreads();
    }
    #pragma unroll
    for (int mf = 0; mf < 3; ++mf)
        #pragma unroll
        for (int nf = 0; nf < 2; ++nf) {
            int cc = col0 + wn*32 + nf*16 + l16;
            if (cc < N) {
                #pragma unroll
                for (int r = 0; r < 4; ++r) {
                    int rr = wm*48 + mf*16 + g*4 + r;
                    C[(size_t)rr*N + cc] = acc[mf][nf][r];
                }
            }
        }
}

// ---------------------------------------------------------------------------
__global__ void k_cnt(const int* __restrict__ et, uint2* __restrict__ cnt)
{
    int b = blockIdx.x;
    int k = threadIdx.x;
    if (k >= TT) return;
    unsigned lo = 0, hi = 0;
    for (int i = 0; i < TT; ++i) {
        int r = et[(b*TT + i)*TT + k];
        if (r < 4) lo += 1u << (8*r); else hi += 1u << (8*(r-4));
        cnt[(b*TT + i)*TT + k] = make_uint2(lo, hi);
    }
}

__global__ __launch_bounds__(256) void k_absdiag(float* __restrict__ Q,
        const uint2* __restrict__ cnt, const float* __restrict__ rel)
{
    int bt = blockIdx.x; int b = bt / TT, t = bt % TT;
    uint2 c = cnt[(b*TT + t)*TT + t];
    float cr[8];
    cr[0] = (float)( c.x        & 0xff); cr[1] = (float)((c.x >>  8) & 0xff);
    cr[2] = (float)((c.x >> 16) & 0xff); cr[3] = (float)((c.x >> 24) & 0xff);
    cr[4] = (float)( c.y        & 0xff); cr[5] = (float)((c.y >>  8) & 0xff);
    cr[6] = (float)((c.y >> 16) & 0xff); cr[7] = (float)((c.y >> 24) & 0xff);
    float* q = Q + (size_t)bt*DD;
    for (int d = threadIdx.x; d < DD; d += 256) {
        float a = q[d];
        #pragma unroll
        for (int r = 0; r < 8; ++r) a += cr[r]*rel[r*DD + d];
        q[d] = a;
    }
}

__global__ void k_ar(const float* __restrict__ Q, const float* __restrict__ rel,
                     float* __restrict__ AR)
{
    int bt = blockIdx.x;
    int t = threadIdx.x;            // 0..127 : h*8 + r
    int h = t / 8, r = t % 8;
    const float* q  = Q + (size_t)bt*DD + h*DH;
    const float* rl = rel + r*DD + h*DH;
    float s = 0.0f;
    #pragma unroll 16
    for (int d = 0; d < DH; ++d) s += q[d]*rl[d];
    AR[bt*128 + t] = s;
}

// Fused scores + softmax + PV per (b,h,i) row; wave-parallel softmax, 2-wave PV
__global__ __launch_bounds__(128) void k_attn_row(const float* __restrict__ A,
        const float* __restrict__ K, const float* __restrict__ V,
        const uint2* __restrict__ cnt, const float* __restrict__ AR,
        const int* __restrict__ mask, float* __restrict__ out)
{
    int bid = blockIdx.x;
    int b = bid / (HH*TT);
    int h = (bid / TT) % HH;
    int i = bid % TT;
    __shared__ float a_sh[DH];
    __shared__ float ar_sh[8];
    __shared__ float sc[TT];
    __shared__ float redm[2], reds[2];
    __shared__ float osh[DH];
    int t = threadIdx.x;
    int lane = t & 63, w = t >> 6;
    if (t < DH)            a_sh[t]      = A[((size_t)(b*TT + i))*DD + h*DH + t];
    else if (t < DH + 8)   ar_sh[t-DH]  = AR[(b*TT + i)*128 + h*8 + (t - DH)];
    __syncthreads();
    if (t < TT) {
        const float* kr = K + ((size_t)(b*TT + t))*DD + h*DH;
        float s = 0.0f;
        #pragma unroll 16
        for (int d = 0; d < DH; ++d) s += a_sh[d]*kr[d];
        uint2 c = cnt[(b*TT + i)*TT + t];
        float s2 = (float)( c.x        & 0xff)*ar_sh[0] + (float)((c.x >>  8) & 0xff)*ar_sh[1]
                 + (float)((c.x >> 16) & 0xff)*ar_sh[2] + (float)((c.x >> 24) & 0xff)*ar_sh[3]
                 + (float)( c.y        & 0xff)*ar_sh[4] + (float)((c.y >>  8) & 0xff)*ar_sh[5]
                 + (float)((c.y >> 16) & 0xff)*ar_sh[6] + (float)((c.y >> 24) & 0xff)*ar_sh[7];
        int m = mask[(b*TT + i)*TT + t];
        sc[t] = (m == 0) ? -1e9f : (s + s2)*0.125f;
    }
    __syncthreads();
    float v = (t < TT) ? sc[t] : -1e30f;
    #pragma unroll
    for (int off = 32; off; off >>= 1) v = fmaxf(v, __shfl_xor(v, off));
    if (lane == 0) redm[w] = v;
    __syncthreads();
    float mx = fmaxf(redm[0], redm[1]);
    float e = (t < TT) ? __expf(sc[t] - mx) : 0.0f;
    float s = e;
    #pragma unroll
    for (int off = 32; off; off >>= 1) s += __shfl_xor(s, off);
    if (lane == 0) reds[w] = s;
    __syncthreads();
    float inv = 1.0f / (reds[0] + reds[1]);
    if (t < TT) sc[t] = e * inv;
    __syncthreads();
    // PV split across 2 waves (36 keys each)
    float o = 0.0f;
    if (lane < DH) {
        int k2a = w*36;
        for (int k2 = k2a; k2 < k2a + 36; ++k2)
            o += sc[k2]*V[((size_t)(b*TT + k2))*DD + h*DH + lane];
        if (w == 1) osh[lane] = o;
    }
    __syncthreads();
    if (w == 0 && lane < DH)
        out[((size_t)(b*TT + i))*DD + h*DH + lane] = o + osh[lane];
}

// split outputs: emo_trans, delta (+ last_stra_state, last_delta)
__global__ __launch_bounds__(256) void k_final(const float* __restrict__ outs,
        const float* __restrict__ sem_cls, float* __restrict__ o_last_stra,
        float* __restrict__ o_emo, float* __restrict__ o_last_delta,
        float* __restrict__ delta)
{
    int bid = blockIdx.x; int b = bid / UU, u = bid % UU;
    const float* sem = outs + ((size_t)(b*TT + 3*u))*DD;
    const float* st  = sem + DD;
    const float* em  = st + DD;
    const float* sc  = sem_cls + ((size_t)(b*UU + u))*DD;
    float* de = delta + ((size_t)(b*UU + u))*DD;
    float* oe = o_emo + ((size_t)(b*UU + u))*DD;
    for (int d = threadIdx.x; d < DD; d += 256) {
        float dl = sem[d] - sc[d];
        de[d] = dl; oe[d] = em[d];
        if (u == UU-1) { o_last_stra[b*DD + d] = st[d]; o_last_delta[b*DD + d] = dl; }
    }
}

__global__ void k_logits(const float* __restrict__ outs,
        const float* __restrict__ strW, const float* __restrict__ strB,
        const float* __restrict__ emoW, const float* __restrict__ emoB,
        float* __restrict__ o_str, float* __restrict__ o_emo)
{
    int bid = blockIdx.x; int b = bid / UU, u = bid % UU;
    int t = threadIdx.x;
    const float* st = outs + ((size_t)(b*TT + 3*u + 1))*DD;
    const float* em = st + DD;
    if (t < 8) {
        float s = strB[t];
        for (int k = 0; k < DD; ++k) s += st[k]*strW[k*8 + t];
        o_str[(b*UU + u)*8 + t] = s;
    } else if (t < 14) {
        int j = t - 8;
        float s = emoB[j];
        for (int k = 0; k < DD; ++k) s += em[k]*emoW[k*6 + j];
        o_emo[(b*UU + u)*6 + j] = s;
    }
}

// ---------------------------------------------------------------------------
extern "C" void kernel_launch(void* const* d_in, const int* in_sizes, int n_in,
                              void* d_out, int out_size, void* d_ws, size_t ws_size,
                              hipStream_t stream)
{
    const float* hidden  = (const float*)d_in[0];
    const float* emo_csk = (const float*)d_in[1];
    const float* Wq  = (const float*)d_in[2];
    const float* bq  = (const float*)d_in[3];
    const float* Wk  = (const float*)d_in[4];
    const float* bk  = (const float*)d_in[5];
    const float* Wv  = (const float*)d_in[6];
    const float* bv  = (const float*)d_in[7];
    const float* rel = (const float*)d_in[8];
    const float* fusW = (const float*)d_in[9];
    const float* fusB = (const float*)d_in[10];
    const float* bng = (const float*)d_in[11];
    const float* bnb = (const float*)d_in[12];
    const float* bnm = (const float*)d_in[13];
    const float* bnv = (const float*)d_in[14];
    const float* cskW = (const float*)d_in[15];
    const float* cskB = (const float*)d_in[16];
    const float* emoW = (const float*)d_in[17];
    const float* emoB = (const float*)d_in[18];
    const float* strW = (const float*)d_in[19];
    const float* strB = (const float*)d_in[20];
    const float* bowW = (const float*)d_in[21];
    const int* clsIdx = (const int*)d_in[22];
    const int* tGraph = (const int*)d_in[23];
    const int* iGraph = (const int*)d_in[24];
    const int* tEdge  = (const int*)d_in[25];
    const int* iEdge  = (const int*)d_in[26];

    float* out = (float*)d_out;
    float* o_last_stra  = out;             // B*D          = 8192
    float* o_emo_trans  = out + 8192;      // B*U*D        = 196608
    float* o_last_delta = out + 204800;    // B*D          = 8192
    float* o_sem_cls    = out + 212992;    // B*U*D        = 196608
    float* o_str_log    = out + 409600;    // B*U*8        = 1536
    float* o_emo_log    = out + 411136;    // B*U*6        = 1152
    float* o_bow        = out + 412288;    // B*U*VOCAB

    float* ws = (float*)d_ws;
    const int SZ_BTD = BB*TT*DD;   // 589824
    const int SZ_BUD = BB*UU*DD;   // 196608
    float* trans_in  = ws;
    float* Qb        = trans_in + SZ_BTD;
    float* Kb        = Qb + SZ_BTD;
    float* Vb        = Kb + SZ_BTD;
    float* trans_out = Vb + SZ_BTD;
    float* inter_out = trans_out + SZ_BTD;
    float* outsB     = inter_out + SZ_BTD;
    float* csk_norm  = outsB + SZ_BTD;
    float* csk_proj  = csk_norm + SZ_BUD;
    float* delta     = csk_proj + SZ_BUD;
    float* ARb       = delta + SZ_BUD;                 // B*T*128
    uint2* cntb      = (uint2*)(ARb + BB*TT*128);      // B*T*T uint2

    // 1. gather cls + build trans_in; write sem_cls_embs
    k_gather_cls<<<dim3(BB*UU), dim3(256), 0, stream>>>(hidden, clsIdx, o_sem_cls, trans_in);
    // 2. batchnorm
    int nbn = BB*UU*CSKN;
    k_bn<<<dim3((nbn+255)/256), dim3(256), 0, stream>>>(emo_csk, bng, bnb, bnm, bnv, csk_norm, nbn);
    // 3. csk_proj = csk_norm @ csk_W + csk_b ; add into trans_in[:,2::3]
    mm_mfma<2,2,2,2,1><<<dim3(DD/64, 192/64), dim3(256), 0, stream>>>(csk_norm, nullptr, CSKN, cskW, cskB, nullptr, nullptr, csk_proj, 192, DD, CSKN);
    k_addcsk<<<dim3(BB*(UU-1)), dim3(256), 0, stream>>>(csk_proj, trans_in);

    // attention helper
    auto attention = [&](const float* x, const int* graph, const int* edge, float* ctx_out) {
        mm_qkv<<<dim3(48, (BB*TT)/64), dim3(256), 0, stream>>>(x, Wq, Wk, Wv, bq, bk, bv, Qb, Kb, Vb);
        k_cnt<<<dim3(BB), dim3(128), 0, stream>>>(edge, cntb);
        k_absdiag<<<dim3(BB*TT), dim3(256), 0, stream>>>(Qb, cntb, rel);
        k_ar<<<dim3(BB*TT), dim3(128), 0, stream>>>(Qb, rel, ARb);
        k_attn_row<<<dim3(BB*HH*TT), dim3(128), 0, stream>>>(Qb, Kb, Vb, cntb, ARb, graph, ctx_out);
    };
    attention(trans_in, tGraph, tEdge, trans_out);
    attention(trans_out, iGraph, iEdge, inter_out);

    // fusion gate + blend fused: outsB = g*trans + (1-g)*inter
    mm_mfma<2,2,2,2,3><<<dim3(DD/64, (BB*TT)/64), dim3(256), 0, stream>>>(trans_out, inter_out, DD, fusW, fusB, trans_out, inter_out, outsB, BB*TT, DD, 2*DD);

    // epilogue splits + small logits
    k_final<<<dim3(BB*UU), dim3(256), 0, stream>>>(outsB, o_sem_cls, o_last_stra, o_emo_trans, o_last_delta, delta);
    k_logits<<<dim3(BB*UU), dim3(64), 0, stream>>>(outsB, strW, strB, emoW, emoB, o_str_log, o_emo_log);

    // bow_logits = delta @ bow_W
    mm_bow<<<dim3((NVOCAB+63)/64), dim3(512), 0, stream>>>(delta, bowW, o_bow);
}

// Round 4
// 346.894 us; speedup vs baseline: 4.0260x; 1.6345x over previous
//
#include <hip/hip_runtime.h>
#include <math.h>

// Problem constants
#define BB 8
#define LL 512
#define UU 24
#define DD 1024
#define HH 16
#define DH 64
#define TT 72
#define CSKN 1024
#define NVOCAB 54945

typedef __attribute__((ext_vector_type(8))) short bf16x8;
typedef __attribute__((ext_vector_type(4))) float f32x4;

__device__ inline unsigned short f2b(float x) {
    unsigned u = __float_as_uint(x);
    unsigned r = u + 0x7FFFu + ((u >> 16) & 1u);
    return (unsigned short)(r >> 16);
}
__device__ inline unsigned pack2(float lo, float hi) {
    return (unsigned)f2b(lo) | ((unsigned)f2b(hi) << 16);
}

// ---------------------------------------------------------------------------
__global__ __launch_bounds__(256) void k_gather_cls(const float* __restrict__ hidden,
        const int* __restrict__ idx, float* __restrict__ sem_cls, float* __restrict__ trans_in)
{
    int bid = blockIdx.x; int b = bid / UU, u = bid % UU;
    int row = idx[b*UU + u];
    const float* src = hidden + ((size_t)(b*LL + row))*DD;
    float* d0 = trans_in + ((size_t)(b*TT + 3*u))*DD;
    float* sc = sem_cls + ((size_t)(b*UU + u))*DD;
    for (int d = threadIdx.x; d < DD; d += 256) {
        float v = src[d];
        sc[d] = v;
        d0[d] = v; d0[DD + d] = v; d0[2*DD + d] = v;
    }
}

__global__ void k_bn(const float* __restrict__ x, const float* __restrict__ g,
                     const float* __restrict__ be, const float* __restrict__ mu,
                     const float* __restrict__ var, float* __restrict__ y, int n)
{
    int i = blockIdx.x*256 + threadIdx.x;
    if (i >= n) return;
    int c = i % CSKN;
    y[i] = (x[i] - mu[c]) * (1.0f/sqrtf(var[c] + 1e-5f)) * g[c] + be[c];
}

// ---------------------------------------------------------------------------
// Double-buffered MFMA bf16 GEMM, 64x64 tile, 256 thr, 4 waves (2x2).
// EPI: 1 = C=A@B+bias ; 3 = gate-blend C=g*ep1+(1-g)*ep2, g=sigmoid(A@B+bias)
//      4 = csk: trans_in[b*72+3u+2][cc] += (A@B+bias), skip u==U-1 (C=trans_in)
template<int EPI>
__global__ __launch_bounds__(256) void mm64(
        const float* __restrict__ A1, const float* __restrict__ A2, int K1,
        const float* __restrict__ Bm, const float* __restrict__ bias,
        const float* __restrict__ ep1, const float* __restrict__ ep2,
        float* __restrict__ C, int N, int K)
{
    __shared__ __align__(16) unsigned short As[2][64][40];
    __shared__ __align__(16) unsigned short Bs[2][64][40];
    int tid = threadIdx.x;
    int wave = tid >> 6, lane = tid & 63;
    int l16 = lane & 15, g = lane >> 4;
    int wm = wave & 1, wn = wave >> 1;
    int row0 = blockIdx.y * 64, col0 = blockIdx.x * 64;

    int ar = tid >> 2, akq = (tid & 3) * 8;        // A slot: row, k-chunk
    int bj0 = (tid & 31) * 2, bk0 = (tid >> 5) * 2; // B slot: col-pair, row-pair
    float4 a0, a1;
    float2 q00, q01, q10, q11;                      // [p][row]

    auto loadT = [&](int k0) {
        int kk = k0 + akq;
        const float* src = (kk < K1) ? A1 + (size_t)(row0+ar)*K1 + kk
                                     : A2 + (size_t)(row0+ar)*(K-K1) + (kk-K1);
        a0 = *(const float4*)src; a1 = *(const float4*)(src+4);
        const float* bs0 = Bm + (size_t)(k0 + bk0)*N + col0 + bj0;
        q00 = *(const float2*)bs0;       q01 = *(const float2*)(bs0 + N);
        const float* bs1 = bs0 + (size_t)16*N;
        q10 = *(const float2*)bs1;       q11 = *(const float2*)(bs1 + N);
    };
    auto storeT = [&](int buf) {
        unsigned* da = (unsigned*)&As[buf][ar][akq];
        da[0] = pack2(a0.x, a0.y); da[1] = pack2(a0.z, a0.w);
        da[2] = pack2(a1.x, a1.y); da[3] = pack2(a1.z, a1.w);
        *(unsigned*)&Bs[buf][bj0  ][bk0]    = pack2(q00.x, q01.x);
        *(unsigned*)&Bs[buf][bj0+1][bk0]    = pack2(q00.y, q01.y);
        *(unsigned*)&Bs[buf][bj0  ][bk0+16] = pack2(q10.x, q11.x);
        *(unsigned*)&Bs[buf][bj0+1][bk0+16] = pack2(q10.y, q11.y);
    };

    f32x4 acc[2][2] = {};
    loadT(0); storeT(0);
    __syncthreads();
    int nt = K / 32;
    for (int t = 0; t < nt; ++t) {
        int cur = t & 1;
        if (t + 1 < nt) loadT((t+1)*32);
        bf16x8 af[2], bfr[2];
        #pragma unroll
        for (int mf = 0; mf < 2; ++mf) af[mf] = *(const bf16x8*)&As[cur][wm*32 + mf*16 + l16][g*8];
        #pragma unroll
        for (int nf = 0; nf < 2; ++nf) bfr[nf] = *(const bf16x8*)&Bs[cur][wn*32 + nf*16 + l16][g*8];
        #pragma unroll
        for (int mf = 0; mf < 2; ++mf)
            #pragma unroll
            for (int nf = 0; nf < 2; ++nf)
                acc[mf][nf] = __builtin_amdgcn_mfma_f32_16x16x32_bf16(af[mf], bfr[nf], acc[mf][nf], 0, 0, 0);
        if (t + 1 < nt) storeT(cur ^ 1);
        __syncthreads();
    }
    #pragma unroll
    for (int mf = 0; mf < 2; ++mf)
        #pragma unroll
        for (int nf = 0; nf < 2; ++nf) {
            int cc = col0 + wn*32 + nf*16 + l16;
            float bv = bias[cc];
            #pragma unroll
            for (int r = 0; r < 4; ++r) {
                int rr = row0 + wm*32 + mf*16 + g*4 + r;
                float v = acc[mf][nf][r] + bv;
                if (EPI == 1) {
                    C[(size_t)rr*N + cc] = v;
                } else if (EPI == 3) {
                    float gg = 1.0f/(1.0f + __expf(-v));
                    float tv = ep1[(size_t)rr*N + cc];
                    float iv = ep2[(size_t)rr*N + cc];
                    C[(size_t)rr*N + cc] = gg*tv + (1.0f - gg)*iv;
                } else { // EPI == 4
                    int bq = rr / UU, uq = rr % UU;
                    if (uq < UU-1) {
                        float* dst = &C[((size_t)(bq*TT + 3*uq + 2))*DD + cc];
                        *dst += v;
                    }
                }
            }
        }
}

// ---------------------------------------------------------------------------
// Fused Q/K/V projection, double-buffered. Grid (48, 9); blockIdx.x>>4 selects.
__global__ __launch_bounds__(256) void mm_qkv(
        const float* __restrict__ x,
        const float* __restrict__ W0, const float* __restrict__ W1, const float* __restrict__ W2,
        const float* __restrict__ v0, const float* __restrict__ v1, const float* __restrict__ v2,
        float* __restrict__ C0, float* __restrict__ C1, float* __restrict__ C2)
{
    __shared__ __align__(16) unsigned short As[2][64][40];
    __shared__ __align__(16) unsigned short Bs[2][64][40];
    int which = blockIdx.x >> 4;
    int col0 = (blockIdx.x & 15) * 64;
    int row0 = blockIdx.y * 64;
    const float* W  = (which == 0) ? W0 : (which == 1) ? W1 : W2;
    const float* bb = (which == 0) ? v0 : (which == 1) ? v1 : v2;
    float*       C  = (which == 0) ? C0 : (which == 1) ? C1 : C2;
    int tid = threadIdx.x;
    int wave = tid >> 6, lane = tid & 63;
    int l16 = lane & 15, g = lane >> 4;
    int wm = wave & 1, wn = wave >> 1;

    int ar = tid >> 2, akq = (tid & 3) * 8;
    int bj0 = (tid & 31) * 2, bk0 = (tid >> 5) * 2;
    float4 a0, a1;
    float2 q00, q01, q10, q11;

    auto loadT = [&](int k0) {
        const float* src = x + (size_t)(row0+ar)*DD + k0 + akq;
        a0 = *(const float4*)src; a1 = *(const float4*)(src+4);
        const float* bs0 = W + (size_t)(k0 + bk0)*DD + col0 + bj0;
        q00 = *(const float2*)bs0;       q01 = *(const float2*)(bs0 + DD);
        const float* bs1 = bs0 + (size_t)16*DD;
        q10 = *(const float2*)bs1;       q11 = *(const float2*)(bs1 + DD);
    };
    auto storeT = [&](int buf) {
        unsigned* da = (unsigned*)&As[buf][ar][akq];
        da[0] = pack2(a0.x, a0.y); da[1] = pack2(a0.z, a0.w);
        da[2] = pack2(a1.x, a1.y); da[3] = pack2(a1.z, a1.w);
        *(unsigned*)&Bs[buf][bj0  ][bk0]    = pack2(q00.x, q01.x);
        *(unsigned*)&Bs[buf][bj0+1][bk0]    = pack2(q00.y, q01.y);
        *(unsigned*)&Bs[buf][bj0  ][bk0+16] = pack2(q10.x, q11.x);
        *(unsigned*)&Bs[buf][bj0+1][bk0+16] = pack2(q10.y, q11.y);
    };

    f32x4 acc[2][2] = {};
    loadT(0); storeT(0);
    __syncthreads();
    for (int t = 0; t < 32; ++t) {
        int cur = t & 1;
        if (t < 31) loadT((t+1)*32);
        bf16x8 af[2], bfr[2];
        #pragma unroll
        for (int mf = 0; mf < 2; ++mf) af[mf] = *(const bf16x8*)&As[cur][wm*32 + mf*16 + l16][g*8];
        #pragma unroll
        for (int nf = 0; nf < 2; ++nf) bfr[nf] = *(const bf16x8*)&Bs[cur][wn*32 + nf*16 + l16][g*8];
        #pragma unroll
        for (int mf = 0; mf < 2; ++mf)
            #pragma unroll
            for (int nf = 0; nf < 2; ++nf)
                acc[mf][nf] = __builtin_amdgcn_mfma_f32_16x16x32_bf16(af[mf], bfr[nf], acc[mf][nf], 0, 0, 0);
        if (t < 31) storeT(cur ^ 1);
        __syncthreads();
    }
    #pragma unroll
    for (int mf = 0; mf < 2; ++mf)
        #pragma unroll
        for (int nf = 0; nf < 2; ++nf) {
            int cc = col0 + wn*32 + nf*16 + l16;
            float bv = bb[cc];
            #pragma unroll
            for (int r = 0; r < 4; ++r) {
                int rr = row0 + wm*32 + mf*16 + g*4 + r;
                C[(size_t)rr*DD + cc] = acc[mf][nf][r] + bv;
            }
        }
}

// ---------------------------------------------------------------------------
// bow GEMM: deltaB(bf16)[192,1024] @ bowW[1024,54945]. 512 thr, 8 waves,
// BM=192 BN=128, double-buffered.
__global__ __launch_bounds__(512) void mm_bow(
        const unsigned short* __restrict__ Ab, const float* __restrict__ Bm,
        float* __restrict__ C)
{
    __shared__ __align__(16) unsigned short As[2][192][40];
    __shared__ __align__(16) unsigned short Bs[2][128][40];
    const int N = NVOCAB;
    int tid = threadIdx.x;
    int wave = tid >> 6, lane = tid & 63;
    int l16 = lane & 15, g = lane >> 4;
    int wm = wave & 3, wn = wave >> 2;
    int col0 = blockIdx.x * 128;

    int ar0 = tid >> 2, ak0 = (tid & 3) * 8;
    int ar1 = (tid + 512) >> 2;
    bool hasA1 = (tid < 256);
    int bj0 = (tid & 63) * 2, bk0 = (tid >> 6) * 2;
    int cc0 = col0 + bj0;
    int4 aA, aB;
    float2 q00, q01, q10, q11;

    auto loadT = [&](int k0) {
        aA = *(const int4*)(Ab + (size_t)ar0*DD + k0 + ak0);
        if (hasA1) aB = *(const int4*)(Ab + (size_t)ar1*DD + k0 + ak0);
        const float* bs0 = Bm + (size_t)(k0 + bk0)*N + cc0;
        const float* bs1 = bs0 + (size_t)16*N;
        if (cc0 + 1 < N) {
            q00 = *(const float2*)bs0;  q01 = *(const float2*)(bs0 + N);
            q10 = *(const float2*)bs1;  q11 = *(const float2*)(bs1 + N);
        } else if (cc0 < N) {
            q00 = make_float2(bs0[0], 0.f); q01 = make_float2(bs0[N], 0.f);
            q10 = make_float2(bs1[0], 0.f); q11 = make_float2(bs1[N], 0.f);
        } else {
            q00 = make_float2(0.f,0.f); q01 = q00; q10 = q00; q11 = q00;
        }
    };
    auto storeT = [&](int buf) {
        *(int4*)&As[buf][ar0][ak0] = aA;
        if (hasA1) *(int4*)&As[buf][ar1][ak0] = aB;
        *(unsigned*)&Bs[buf][bj0  ][bk0]    = pack2(q00.x, q01.x);
        *(unsigned*)&Bs[buf][bj0+1][bk0]    = pack2(q00.y, q01.y);
        *(unsigned*)&Bs[buf][bj0  ][bk0+16] = pack2(q10.x, q11.x);
        *(unsigned*)&Bs[buf][bj0+1][bk0+16] = pack2(q10.y, q11.y);
    };

    f32x4 acc[3][4] = {};
    loadT(0); storeT(0);
    __syncthreads();
    for (int t = 0; t < 32; ++t) {
        int cur = t & 1;
        if (t < 31) loadT((t+1)*32);
        bf16x8 af[3], bfr[4];
        #pragma unroll
        for (int mf = 0; mf < 3; ++mf) af[mf] = *(const bf16x8*)&As[cur][wm*48 + mf*16 + l16][g*8];
        #pragma unroll
        for (int nf = 0; nf < 4; ++nf) bfr[nf] = *(const bf16x8*)&Bs[cur][wn*64 + nf*16 + l16][g*8];
        #pragma unroll
        for (int mf = 0; mf < 3; ++mf)
            #pragma unroll
            for (int nf = 0; nf < 4; ++nf)
                acc[mf][nf] = __builtin_amdgcn_mfma_f32_16x16x32_bf16(af[mf], bfr[nf], acc[mf][nf], 0, 0, 0);
        if (t < 31) storeT(cur ^ 1);
        __syncthreads();
    }
    #pragma unroll
    for (int mf = 0; mf < 3; ++mf)
        #pragma unroll
        for (int nf = 0; nf < 4; ++nf) {
            int cc = col0 + wn*64 + nf*16 + l16;
            if (cc < N) {
                #pragma unroll
                for (int r = 0; r < 4; ++r) {
                    int rr = wm*48 + mf*16 + g*4 + r;
                    C[(size_t)rr*N + cc] = acc[mf][nf][r];
                }
            }
        }
}

// ---------------------------------------------------------------------------
__global__ void k_cnt(const int* __restrict__ et, uint2* __restrict__ cnt)
{
    int b = blockIdx.x;
    int k = threadIdx.x;
    if (k >= TT) return;
    unsigned lo = 0, hi = 0;
    for (int i = 0; i < TT; ++i) {
        int r = et[(b*TT + i)*TT + k];
        if (r < 4) lo += 1u << (8*r); else hi += 1u << (8*(r-4));
        cnt[(b*TT + i)*TT + k] = make_uint2(lo, hi);
    }
}

// Fused: A = Q + S_diag (in place) and AR[b,t,h,r] = <A_head, rel_head>
__global__ __launch_bounds__(256) void k_prep(float* __restrict__ Q,
        const uint2* __restrict__ cnt, const float* __restrict__ rel,
        float* __restrict__ AR)
{
    __shared__ float a_loc[DD];
    int bt = blockIdx.x; int b = bt / TT, t = bt % TT;
    uint2 c = cnt[(b*TT + t)*TT + t];
    float cr[8];
    cr[0] = (float)( c.x        & 0xff); cr[1] = (float)((c.x >>  8) & 0xff);
    cr[2] = (float)((c.x >> 16) & 0xff); cr[3] = (float)((c.x >> 24) & 0xff);
    cr[4] = (float)( c.y        & 0xff); cr[5] = (float)((c.y >>  8) & 0xff);
    cr[6] = (float)((c.y >> 16) & 0xff); cr[7] = (float)((c.y >> 24) & 0xff);
    float* q = Q + (size_t)bt*DD;
    for (int d = threadIdx.x; d < DD; d += 256) {
        float a = q[d];
        #pragma unroll
        for (int r = 0; r < 8; ++r) a += cr[r]*rel[r*DD + d];
        q[d] = a; a_loc[d] = a;
    }
    __syncthreads();
    int tt = threadIdx.x;
    if (tt < 128) {
        int h = tt >> 3, r = tt & 7;
        const float* rl = rel + r*DD + h*DH;
        const float* al = a_loc + h*DH;
        float s = 0.0f;
        #pragma unroll 16
        for (int d = 0; d < DH; ++d) s += al[d]*rl[d];
        AR[bt*128 + tt] = s;
    }
}

// Fused scores + softmax + PV per (b,h,i) row; K staged transposed in LDS.
__global__ __launch_bounds__(128) void k_attn_row(const float* __restrict__ A,
        const float* __restrict__ Kg, const float* __restrict__ V,
        const uint2* __restrict__ cnt, const float* __restrict__ AR,
        const int* __restrict__ mask, float* __restrict__ out)
{
    int bid = blockIdx.x;
    int b = bid / (HH*TT);
    int h = (bid / TT) % HH;
    int i = bid % TT;
    __shared__ float K_sh[DH][73];
    __shared__ float a_sh[DH];
    __shared__ float ar_sh[8];
    __shared__ float sc[TT];
    __shared__ float redm[2], reds[2];
    __shared__ float osh[DH];
    int t = threadIdx.x;
    int lane = t & 63, w = t >> 6;
    if (t < DH)           a_sh[t]     = A[((size_t)(b*TT + i))*DD + h*DH + t];
    else if (t < DH + 8)  ar_sh[t-DH] = AR[(b*TT + i)*128 + h*8 + (t - DH)];
    #pragma unroll
    for (int p = 0; p < 9; ++p) {
        int idx = t + p*128;
        int r = idx >> 4, q4 = (idx & 15) * 4;
        float4 kv = *(const float4*)&Kg[((size_t)(b*TT + r))*DD + h*DH + q4];
        K_sh[q4  ][r] = kv.x; K_sh[q4+1][r] = kv.y;
        K_sh[q4+2][r] = kv.z; K_sh[q4+3][r] = kv.w;
    }
    __syncthreads();
    if (t < TT) {
        float s = 0.0f;
        #pragma unroll 16
        for (int d = 0; d < DH; ++d) s += a_sh[d]*K_sh[d][t];
        uint2 c = cnt[(b*TT + i)*TT + t];
        float s2 = (float)( c.x        & 0xff)*ar_sh[0] + (float)((c.x >>  8) & 0xff)*ar_sh[1]
                 + (float)((c.x >> 16) & 0xff)*ar_sh[2] + (float)((c.x >> 24) & 0xff)*ar_sh[3]
                 + (float)( c.y        & 0xff)*ar_sh[4] + (float)((c.y >>  8) & 0xff)*ar_sh[5]
                 + (float)((c.y >> 16) & 0xff)*ar_sh[6] + (float)((c.y >> 24) & 0xff)*ar_sh[7];
        int m = mask[(b*TT + i)*TT + t];
        sc[t] = (m == 0) ? -1e9f : (s + s2)*0.125f;
    }
    __syncthreads();
    float v = (t < TT) ? sc[t] : -1e30f;
    #pragma unroll
    for (int off = 32; off; off >>= 1) v = fmaxf(v, __shfl_xor(v, off));
    if (lane == 0) redm[w] = v;
    __syncthreads();
    float mx = fmaxf(redm[0], redm[1]);
    float e = (t < TT) ? __expf(sc[t] - mx) : 0.0f;
    float s = e;
    #pragma unroll
    for (int off = 32; off; off >>= 1) s += __shfl_xor(s, off);
    if (lane == 0) reds[w] = s;
    __syncthreads();
    float inv = 1.0f / (reds[0] + reds[1]);
    if (t < TT) sc[t] = e * inv;
    __syncthreads();
    float o = 0.0f;
    if (lane < DH) {
        int k2a = w*36;
        for (int k2 = k2a; k2 < k2a + 36; ++k2)
            o += sc[k2]*V[((size_t)(b*TT + k2))*DD + h*DH + lane];
        if (w == 1) osh[lane] = o;
    }
    __syncthreads();
    if (w == 0 && lane < DH)
        out[((size_t)(b*TT + i))*DD + h*DH + lane] = o + osh[lane];
}

// split outputs: emo_trans, delta(bf16) (+ last_stra_state, last_delta)
__global__ __launch_bounds__(256) void k_final(const float* __restrict__ outs,
        const float* __restrict__ sem_cls, float* __restrict__ o_last_stra,
        float* __restrict__ o_emo, float* __restrict__ o_last_delta,
        unsigned short* __restrict__ deltaB)
{
    int bid = blockIdx.x; int b = bid / UU, u = bid % UU;
    const float* sem = outs + ((size_t)(b*TT + 3*u))*DD;
    const float* st  = sem + DD;
    const float* em  = st + DD;
    const float* sc  = sem_cls + ((size_t)(b*UU + u))*DD;
    unsigned short* de = deltaB + ((size_t)(b*UU + u))*DD;
    float* oe = o_emo + ((size_t)(b*UU + u))*DD;
    for (int d = threadIdx.x; d < DD; d += 256) {
        float dl = sem[d] - sc[d];
        de[d] = f2b(dl); oe[d] = em[d];
        if (u == UU-1) { o_last_stra[b*DD + d] = st[d]; o_last_delta[b*DD + d] = dl; }
    }
}

// strategy (8) and emotion (6) logits — parallel partial sums
__global__ __launch_bounds__(256) void k_logits(const float* __restrict__ outs,
        const float* __restrict__ strW, const float* __restrict__ strB,
        const float* __restrict__ emoW, const float* __restrict__ emoB,
        float* __restrict__ o_str, float* __restrict__ o_emo)
{
    __shared__ float part[14][16];
    int bid = blockIdx.x; int b = bid / UU, u = bid % UU;
    const float* st = outs + ((size_t)(b*TT + 3*u + 1))*DD;
    const float* em = st + DD;
    int t = threadIdx.x;
    if (t < 224) {
        int o = t >> 4, c = t & 15;
        float s = 0.0f;
        if (o < 8) {
            for (int d = c*64; d < c*64 + 64; ++d) s += st[d]*strW[d*8 + o];
        } else {
            int j = o - 8;
            for (int d = c*64; d < c*64 + 64; ++d) s += em[d]*emoW[d*6 + j];
        }
        part[o][c] = s;
    }
    __syncthreads();
    if (t < 14) {
        float s = 0.0f;
        #pragma unroll
        for (int c2 = 0; c2 < 16; ++c2) s += part[t][c2];
        if (t < 8) o_str[(b*UU + u)*8 + t] = s + strB[t];
        else       o_emo[(b*UU + u)*6 + (t-8)] = s + emoB[t-8];
    }
}

// ---------------------------------------------------------------------------
extern "C" void kernel_launch(void* const* d_in, const int* in_sizes, int n_in,
                              void* d_out, int out_size, void* d_ws, size_t ws_size,
                              hipStream_t stream)
{
    const float* hidden  = (const float*)d_in[0];
    const float* emo_csk = (const float*)d_in[1];
    const float* Wq  = (const float*)d_in[2];
    const float* bq  = (const float*)d_in[3];
    const float* Wk  = (const float*)d_in[4];
    const float* bk  = (const float*)d_in[5];
    const float* Wv  = (const float*)d_in[6];
    const float* bv  = (const float*)d_in[7];
    const float* rel = (const float*)d_in[8];
    const float* fusW = (const float*)d_in[9];
    const float* fusB = (const float*)d_in[10];
    const float* bng = (const float*)d_in[11];
    const float* bnb = (const float*)d_in[12];
    const float* bnm = (const float*)d_in[13];
    const float* bnv = (const float*)d_in[14];
    const float* cskW = (const float*)d_in[15];
    const float* cskB = (const float*)d_in[16];
    const float* emoW = (const float*)d_in[17];
    const float* emoB = (const float*)d_in[18];
    const float* strW = (const float*)d_in[19];
    const float* strB = (const float*)d_in[20];
    const float* bowW = (const float*)d_in[21];
    const int* clsIdx = (const int*)d_in[22];
    const int* tGraph = (const int*)d_in[23];
    const int* iGraph = (const int*)d_in[24];
    const int* tEdge  = (const int*)d_in[25];
    const int* iEdge  = (const int*)d_in[26];

    float* out = (float*)d_out;
    float* o_last_stra  = out;             // B*D          = 8192
    float* o_emo_trans  = out + 8192;      // B*U*D        = 196608
    float* o_last_delta = out + 204800;    // B*D          = 8192
    float* o_sem_cls    = out + 212992;    // B*U*D        = 196608
    float* o_str_log    = out + 409600;    // B*U*8        = 1536
    float* o_emo_log    = out + 411136;    // B*U*6        = 1152
    float* o_bow        = out + 412288;    // B*U*VOCAB

    float* ws = (float*)d_ws;
    const int SZ_BTD = BB*TT*DD;   // 589824
    const int SZ_BUD = BB*UU*DD;   // 196608
    float* trans_in  = ws;
    float* Qb        = trans_in + SZ_BTD;
    float* Kb        = Qb + SZ_BTD;
    float* Vb        = Kb + SZ_BTD;
    float* trans_out = Vb + SZ_BTD;
    float* inter_out = trans_out + SZ_BTD;
    float* outsB     = inter_out + SZ_BTD;
    float* csk_norm  = outsB + SZ_BTD;
    float* ARb       = csk_norm + SZ_BUD;              // B*T*128
    float* cnt_f     = ARb + BB*TT*128;
    uint2* cntb      = (uint2*)cnt_f;                  // B*T*T uint2
    unsigned short* deltaB = (unsigned short*)(cnt_f + BB*TT*TT*2);

    // 1. gather cls + build trans_in; write sem_cls_embs
    k_gather_cls<<<dim3(BB*UU), dim3(256), 0, stream>>>(hidden, clsIdx, o_sem_cls, trans_in);
    // 2. batchnorm
    int nbn = BB*UU*CSKN;
    k_bn<<<dim3((nbn+255)/256), dim3(256), 0, stream>>>(emo_csk, bng, bnb, bnm, bnv, csk_norm, nbn);
    // 3. csk_proj GEMM fused with scatter-add into trans_in[:,2::3]
    mm64<4><<<dim3(16, 3), dim3(256), 0, stream>>>(csk_norm, nullptr, CSKN, cskW, cskB,
            nullptr, nullptr, trans_in, DD, CSKN);

    auto attention = [&](const float* x, const int* graph, const int* edge, float* ctx_out) {
        mm_qkv<<<dim3(48, (BB*TT)/64), dim3(256), 0, stream>>>(x, Wq, Wk, Wv, bq, bk, bv, Qb, Kb, Vb);
        k_cnt<<<dim3(BB), dim3(128), 0, stream>>>(edge, cntb);
        k_prep<<<dim3(BB*TT), dim3(256), 0, stream>>>(Qb, cntb, rel, ARb);
        k_attn_row<<<dim3(BB*HH*TT), dim3(128), 0, stream>>>(Qb, Kb, Vb, cntb, ARb, graph, ctx_out);
    };
    attention(trans_in, tGraph, tEdge, trans_out);
    attention(trans_out, iGraph, iEdge, inter_out);

    // fusion gate + blend fused: outsB = g*trans + (1-g)*inter
    mm64<3><<<dim3(16, (BB*TT)/64), dim3(256), 0, stream>>>(trans_out, inter_out, DD, fusW, fusB,
            trans_out, inter_out, outsB, DD, 2*DD);

    // epilogue splits (writes deltaB bf16) + small logits
    k_final<<<dim3(BB*UU), dim3(256), 0, stream>>>(outsB, o_sem_cls, o_last_stra, o_emo_trans, o_last_delta, deltaB);
    k_logits<<<dim3(BB*UU), dim3(256), 0, stream>>>(outsB, strW, strB, emoW, emoB, o_str_log, o_emo_log);

    // bow_logits = delta @ bow_W
    mm_bow<<<dim3((NVOCAB+127)/128), dim3(512), 0, stream>>>(deltaB, bowW, o_bow);
}